// Round 3
// baseline (668.264 us; speedup 1.0000x reference)
//
#include <hip/hip_runtime.h>
#include <hip/hip_bf16.h>

#define DIM 128
typedef __hip_bfloat16 bf16;

// typed load/store helpers (all math in f32)
__device__ __forceinline__ float ldv(const float* p, size_t i) { return p[i]; }
__device__ __forceinline__ float ldv(const bf16* p, size_t i) { return __bfloat162float(p[i]); }
__device__ __forceinline__ void stv(float* p, size_t i, float v) { p[i] = v; }
__device__ __forceinline__ void stv(bf16* p, size_t i, float v) { p[i] = __float2bfloat16(v); }

// ============================ mode detection ================================
// flagI: ==0 -> edge_index is int64 (odd 32-bit words of src half all zero)
// flagF: >128 -> x/W/b are float32, else bf16
__global__ void detect_int(const int* __restrict__ w32, int E, int* __restrict__ flagI) {
    int i = blockIdx.x * blockDim.x + threadIdx.x;
    int stride = gridDim.x * blockDim.x;
    int acc = 0;
    for (int j = i; j < E; j += stride) acc |= w32[2 * j + 1];
    if (acc) atomicOr(flagI, 1);
}

__global__ void detect_float(const unsigned short* __restrict__ xu, int* __restrict__ flagF) {
    int i = blockIdx.x * blockDim.x + threadIdx.x;   // 8192 threads
    float f = __uint_as_float(((unsigned int)xu[i]) << 16);
    float a = fabsf(f);
    bool bad = !(a <= 1e20f) || (a != 0.f && a < 1e-20f);
    if (bad) atomicAdd(flagF, 1);
}

// ============================ graph build ===================================
__global__ void count_kernel(const int* __restrict__ ei, int E,
                             const int* __restrict__ flagI, int* __restrict__ cnt) {
    int e = blockIdx.x * blockDim.x + threadIdx.x;
    if (e >= E) return;
    int d = (*flagI == 0) ? ei[2 * E + 2 * e] : ei[E + e];
    atomicAdd(&cnt[d], 1);
}

__global__ void alloc_kernel(const int* __restrict__ cnt, int* __restrict__ rowstart,
                             int* __restrict__ cursor, float* __restrict__ dis,
                             int* __restrict__ head, int N) {
    int i = blockIdx.x * blockDim.x + threadIdx.x;
    if (i >= N) return;
    int c = cnt[i];
    int s = atomicAdd(head, c);
    rowstart[i] = s;
    cursor[i] = s;
    dis[i] = rsqrtf((float)(c + 1));   // +1 self loop
}

__global__ void fill_kernel(const int* __restrict__ ei, int E,
                            const int* __restrict__ flagI,
                            int* __restrict__ cursor, int* __restrict__ csr) {
    int e = blockIdx.x * blockDim.x + threadIdx.x;
    if (e >= E) return;
    int s, d;
    if (*flagI == 0) { s = ei[2 * e]; d = ei[2 * E + 2 * e]; }
    else             { s = ei[e];     d = ei[E + e]; }
    int p = atomicAdd(&cursor[d], 1);
    csr[p] = s;
}

// ============================ gemm ==========================================
// y[node][c] = (X[node,:] @ W[:,c]) * dis[node]; one wave/node, lane = c, c+64
template <typename XT, typename WT, typename YT>
__device__ __forceinline__ void gemm_body(const XT* __restrict__ X, const WT* __restrict__ W,
                                          const float* __restrict__ dis, YT* __restrict__ Y,
                                          int N) {
    int wid = threadIdx.x >> 6, lane = threadIdx.x & 63;
    int node = blockIdx.x * 4 + wid;
    if (node >= N) return;
    size_t base = (size_t)node * DIM;
    float acc0 = 0.f, acc1 = 0.f;
    #pragma unroll 8
    for (int k = 0; k < DIM; ++k) {
        float xv = ldv(X, base + k);                 // wave-broadcast load
        acc0 += xv * ldv(W, (size_t)k * DIM + lane);
        acc1 += xv * ldv(W, (size_t)k * DIM + lane + 64);
    }
    float ds = dis[node];
    stv(Y, base + lane, acc0 * ds);
    stv(Y, base + lane + 64, acc1 * ds);
}

// layer 1: X dtype follows the input mode flag (same as W)
template <typename YT>
__global__ void gemm_l1(const void* X, const void* W, const float* dis, YT* Y, int N,
                        const int* flagF) {
    if (*flagF > 128) gemm_body<float, float, YT>((const float*)X, (const float*)W, dis, Y, N);
    else              gemm_body<bf16, bf16, YT>((const bf16*)X, (const bf16*)W, dis, Y, N);
}

// layer 2: X (= h) dtype known at compile time; W follows flag
template <typename XT, typename YT>
__global__ void gemm_l2(const XT* X, const void* W, const float* dis, YT* Y, int N,
                        const int* flagF) {
    if (*flagF > 128) gemm_body<XT, float, YT>(X, (const float*)W, dis, Y, N);
    else              gemm_body<XT, bf16, YT>(X, (const bf16*)W, dis, Y, N);
}

// ============================ aggregate =====================================
// out[node][c] = relu(dis[node]*(y[node][c] + sum_{src} y[src][c]) + b[c])
template <typename YT, typename OT>
__global__ void aggregate(const YT* __restrict__ Y, const int* __restrict__ rowstart,
                          const int* __restrict__ cnt, const int* __restrict__ csr,
                          const float* __restrict__ dis, const void* __restrict__ bias,
                          OT* __restrict__ Out, int N, const int* flagF) {
    int node = blockIdx.x * 2 + (threadIdx.x >> 7);
    int c = threadIdx.x & 127;
    if (node >= N) return;
    size_t base = (size_t)node * DIM;
    float acc = ldv(Y, base + c);                    // self loop
    int e0 = rowstart[node], e1 = e0 + cnt[node];
    for (int e = e0; e < e1; ++e)
        acc += ldv(Y, (size_t)csr[e] * DIM + c);
    float bv = (*flagF > 128) ? ((const float*)bias)[c]
                              : __bfloat162float(((const bf16*)bias)[c]);
    stv(Out, base + c, fmaxf(dis[node] * acc + bv, 0.f));
}

// final layer: output dtype follows the input mode flag
template <typename YT>
__global__ void aggregate_final(const YT* __restrict__ Y, const int* __restrict__ rowstart,
                                const int* __restrict__ cnt, const int* __restrict__ csr,
                                const float* __restrict__ dis, const void* __restrict__ bias,
                                void* __restrict__ Out, int N, const int* flagF) {
    int node = blockIdx.x * 2 + (threadIdx.x >> 7);
    int c = threadIdx.x & 127;
    if (node >= N) return;
    size_t base = (size_t)node * DIM;
    float acc = ldv(Y, base + c);
    int e0 = rowstart[node], e1 = e0 + cnt[node];
    for (int e = e0; e < e1; ++e)
        acc += ldv(Y, (size_t)csr[e] * DIM + c);
    bool f32m = (*flagF > 128);
    float bv = f32m ? ((const float*)bias)[c] : __bfloat162float(((const bf16*)bias)[c]);
    float v = fmaxf(dis[node] * acc + bv, 0.f);
    if (f32m) ((float*)Out)[base + c] = v;
    else      ((bf16*)Out)[base + c] = __float2bfloat16(v);
}

// ============================ launcher ======================================
extern "C" void kernel_launch(void* const* d_in, const int* in_sizes, int n_in,
                              void* d_out, int out_size, void* d_ws, size_t ws_size,
                              hipStream_t stream) {
    const void* x  = d_in[0];
    const int*  ei = (const int*)d_in[1];
    const void* W1 = d_in[2];
    const void* b1 = d_in[3];
    const void* W2 = d_in[4];
    const void* b2 = d_in[5];

    int N = in_sizes[0] / DIM;      // 50000
    int E = in_sizes[1] / 2;        // 600000

    // --- workspace carve, strictly within ws_size -------------------------
    char* w = (char*)d_ws;
    size_t used = 0;
    auto carve = [&](size_t bytes) {
        char* p = w + used;
        used += (bytes + 255) & ~(size_t)255;
        return p;
    };
    int*   misc     = (int*)  carve(256);               // [0]=head [1]=flagI [2]=flagF
    int*   cnt      = (int*)  carve((size_t)N * 4);     // adjacent to misc (one memset)
    int*   rowstart = (int*)  carve((size_t)N * 4);
    int*   cursor   = (int*)  carve((size_t)N * 4);
    int*   csr      = (int*)  carve((size_t)E * 4);
    float* dis      = (float*)carve((size_t)N * 4);
    size_t fixed = used;
    size_t fbuf = (size_t)N * DIM * 4;                  // 25.6 MB
    size_t bbuf = (size_t)N * DIM * 2;                  // 12.8 MB

    int* head  = misc + 0;
    int* flagI = misc + 1;
    int* flagF = misc + 2;

    hipMemsetAsync(misc, 0, 256 + (size_t)N * 4, stream);   // head/flags + cnt

    detect_int  <<<64, 256, 0, stream>>>(ei, E, flagI);
    detect_float<<<32, 256, 0, stream>>>((const unsigned short*)x, flagF);
    count_kernel<<<(E + 255) / 256, 256, 0, stream>>>(ei, E, flagI, cnt);
    alloc_kernel<<<(N + 255) / 256, 256, 0, stream>>>(cnt, rowstart, cursor, dis, head, N);
    fill_kernel <<<(E + 255) / 256, 256, 0, stream>>>(ei, E, flagI, cursor, csr);

    int gblocks = (N + 3) / 4;
    int ablocks = (N + 1) / 2;

    if (fixed + 2 * fbuf <= ws_size) {
        // tier 1: f32 y, f32 h  (max precision)
        float* ybuf = (float*)carve(fbuf);
        float* hbuf = (float*)carve(fbuf);
        gemm_l1<float><<<gblocks, 256, 0, stream>>>(x, W1, dis, ybuf, N, flagF);
        aggregate<float, float><<<ablocks, 256, 0, stream>>>(ybuf, rowstart, cnt, csr, dis, b1,
                                                             hbuf, N, flagF);
        gemm_l2<float, float><<<gblocks, 256, 0, stream>>>(hbuf, W2, dis, ybuf, N, flagF);
        aggregate_final<float><<<ablocks, 256, 0, stream>>>(ybuf, rowstart, cnt, csr, dis, b2,
                                                            d_out, N, flagF);
    } else if (fixed + bbuf + fbuf <= ws_size) {
        // tier 2: bf16 y, f32 h
        bf16*  ybuf = (bf16*) carve(bbuf);
        float* hbuf = (float*)carve(fbuf);
        gemm_l1<bf16><<<gblocks, 256, 0, stream>>>(x, W1, dis, ybuf, N, flagF);
        aggregate<bf16, float><<<ablocks, 256, 0, stream>>>(ybuf, rowstart, cnt, csr, dis, b1,
                                                            hbuf, N, flagF);
        gemm_l2<float, bf16><<<gblocks, 256, 0, stream>>>(hbuf, W2, dis, ybuf, N, flagF);
        aggregate_final<bf16><<<ablocks, 256, 0, stream>>>(ybuf, rowstart, cnt, csr, dis, b2,
                                                           d_out, N, flagF);
    } else {
        // tier 3 (16 MB): bf16 y in ws, bf16 h staged in d_out (fully rewritten later)
        bf16* ybuf = (bf16*)carve(bbuf);
        bf16* hbuf = (bf16*)d_out;
        gemm_l1<bf16><<<gblocks, 256, 0, stream>>>(x, W1, dis, ybuf, N, flagF);
        aggregate<bf16, bf16><<<ablocks, 256, 0, stream>>>(ybuf, rowstart, cnt, csr, dis, b1,
                                                           hbuf, N, flagF);
        gemm_l2<bf16, bf16><<<gblocks, 256, 0, stream>>>(hbuf, W2, dis, ybuf, N, flagF);
        aggregate_final<bf16><<<ablocks, 256, 0, stream>>>(ybuf, rowstart, cnt, csr, dis, b2,
                                                           d_out, N, flagF);
    }
}